// Round 2
// 147.464 us; speedup vs baseline: 1.0033x; 1.0033x over previous
//
#include <hip/hip_runtime.h>
#include <cstdint>
#include <cstddef>

#define NODES 20000
#define NEDGE 320000
#define CAP 64            // padded CSR capacity per node (max deg ~34 at 16+/-4)
#define NEB 625           // NEDGE/(256*2) -- 2 edges per thread
#define LINB 16           // 4096/256
#define BIGB 32           // 8192/256

using bf16x8 = __attribute__((ext_vector_type(8))) __bf16;
using f32x4  = __attribute__((ext_vector_type(4))) float;
using f32x2  = __attribute__((ext_vector_type(2))) float;
using i32x4  = __attribute__((ext_vector_type(4))) int;   // vector type usable with nontemporal builtins

__device__ __forceinline__ unsigned short f2bf(float f) {
  union { float f; unsigned int u; } v; v.f = f;
  unsigned int r = v.u + 0x7FFF + ((v.u >> 16) & 1);  // RNE
  return (unsigned short)(r >> 16);
}

// decode one packed-fp8 dword and accumulate into 4 f32 lanes
#define DECACC(u, s0, s1, s2, s3)                               \
  {                                                             \
    f32x2 lo_ = __builtin_amdgcn_cvt_pk_f32_fp8(u, false);      \
    f32x2 hi_ = __builtin_amdgcn_cvt_pk_f32_fp8(u, true);       \
    s0 += lo_.x; s1 += lo_.y; s2 += hi_.x; s3 += hi_.y;         \
  }

// ---------------- build: padded-CSR fill + lin->bf16 + BigW (direct) ----------------
// cnt zeroed by hipMemsetAsync before this kernel.
// wb16 layout: [0,4096) lin ; [4096,12288) BigW[128][64]
__global__ void k_build(const int* __restrict__ ei, int* __restrict__ cnt,
                        int* __restrict__ csr,
                        const float* __restrict__ lin, const float* __restrict__ u1,
                        const float* __restrict__ u2, const float* __restrict__ l1,
                        const float* __restrict__ l2, const float* __restrict__ lastw,
                        unsigned short* __restrict__ wb16) {
  __shared__ float tmp_u[4][64];
  __shared__ float tmp_l[4][64];
  int bid = blockIdx.x, t = threadIdx.x;
  if (bid < NEB) {
    int i = (bid * 256 + t) * 2;          // 625*256*2 == NEDGE exactly
    int2 r2 = *(const int2*)(ei + i);
    int2 c2 = *(const int2*)(ei + NEDGE + i);
    int p0 = atomicAdd(&cnt[c2.x], 1);
    if (p0 < CAP) csr[c2.x * CAP + p0] = r2.x;
    int p1 = atomicAdd(&cnt[c2.y], 1);
    if (p1 < CAP) csr[c2.y * CAP + p1] = r2.y;
  } else if (bid < NEB + LINB) {
    int g = (bid - NEB) * 256 + t;  // [0,4096)
    wb16[g] = f2bf(lin[g]);
  } else {
    // BigW[o][j] = sum_p (sum_k last[o][k] u2[k][p]) u1[p][j]
    //            + sum_p (sum_k last[o][64+k] l2[k][p]) l1[p][j]
    int o0 = (bid - NEB - LINB) * 4;
    int ol = t >> 6, p = t & 63;
    float su = 0.f, sl = 0.f;
    for (int k = 0; k < 64; ++k) {
      float lu = lastw[(o0 + ol) * 128 + k];
      float ll = lastw[(o0 + ol) * 128 + 64 + k];
      su += lu * u2[k * 64 + p];
      sl += ll * l2[k * 64 + p];
    }
    tmp_u[ol][p] = su;
    tmp_l[ol][p] = sl;
    __syncthreads();
    int j = p;
    float acc = 0.f;
    for (int q = 0; q < 64; ++q)
      acc += tmp_u[ol][q] * u1[q * 64 + j] + tmp_l[ol][q] * l1[q * 64 + j];
    wb16[4096 + (o0 + ol) * 64 + j] = f2bf(acc);
  }
}

// ---------------- xconv: dis = rsqrt(cnt+1); xs8 = fp8(x * dis) ----------------
__global__ void k_xconv(const int* __restrict__ cnt, float* __restrict__ dis,
                        const float* __restrict__ x, unsigned int* __restrict__ xs8) {
  int g = blockIdx.x * 256 + threadIdx.x;  // [0, NODES*64)
  int n = g >> 6, i = g & 63;
  int b = i >> 4, c = (i & 15) * 4;
  float ds = rsqrtf((float)(cnt[n] + 1));  // +1 = self loop
  if (i == 0) dis[n] = ds;
  f32x4 v = __builtin_nontemporal_load(
      (const f32x4*)(x + ((size_t)b * NODES + n) * 64 + c));
  int p = 0;
  p = __builtin_amdgcn_cvt_pk_fp8_f32(v.x * ds, v.y * ds, p, false);  // bytes 0,1
  p = __builtin_amdgcn_cvt_pk_fp8_f32(v.z * ds, v.w * ds, p, true);   // bytes 2,3
  xs8[(size_t)n * 64 + i] = (unsigned int)p;
}

// ---------------- fused gather(fp8) + lin + sigmoid + BigW + relu ----------------
// block = 8 nodes (32 rows), 4 waves (256 thr); wave gathers 2 nodes INTERLEAVED
// (16-deep MLP: 8 loads in flight per node) with int4 CSR index loads.
// stage1 (swapped): h^T[feat][row] = lin @ xa^T; fst = sigmoid -> LDS packed
// stage2 (natural): D[row][oc] = fst @ BigW^T; oc = lane&15 -> full-line stores
__global__ __launch_bounds__(256) void k_gpost(const int* __restrict__ cnt,
                                               const int* __restrict__ csr,
                                               const unsigned int* __restrict__ xs8,
                                               const float* __restrict__ dis,
                                               const float* __restrict__ bias,
                                               const unsigned short* __restrict__ wb16,
                                               float* __restrict__ out) {
  __shared__ unsigned short xa[32][72];
  __shared__ unsigned short fst[32][72];
  int t = threadIdx.x;
  int w = t >> 6, l = t & 63;
  int n0 = blockIdx.x * 8;
  int nA = n0 + 2 * w;  // wave handles nodes nA, nA+1, interleaved

  int2 cc = *(const int2*)(cnt + nA);
  int dA = cc.x > CAP ? CAP : cc.x;
  int dB = cc.y > CAP ? CAP : cc.y;

  float aA0, aA1, aA2, aA3, aB0, aB1, aB2, aB3;
  {
    unsigned int uA = xs8[(size_t)nA * 64 + l];        // self loop A
    unsigned int uB = xs8[(size_t)(nA + 1) * 64 + l];  // self loop B
    f32x2 lo = __builtin_amdgcn_cvt_pk_f32_fp8(uA, false);
    f32x2 hi = __builtin_amdgcn_cvt_pk_f32_fp8(uA, true);
    aA0 = lo.x; aA1 = lo.y; aA2 = hi.x; aA3 = hi.y;
    lo = __builtin_amdgcn_cvt_pk_f32_fp8(uB, false);
    hi = __builtin_amdgcn_cvt_pk_f32_fp8(uB, true);
    aB0 = lo.x; aB1 = lo.y; aB2 = hi.x; aB3 = hi.y;
  }

  int iA = nA * CAP, eA = iA + dA;
  int iB = iA + CAP, eB = iB + dB;

  // joint 8+8: 16 gather loads + 4 int4 index loads in flight
  while (iA + 8 <= eA && iB + 8 <= eB) {
    i32x4 ra0 = __builtin_nontemporal_load((const i32x4*)(csr + iA));
    i32x4 ra1 = __builtin_nontemporal_load((const i32x4*)(csr + iA + 4));
    i32x4 rb0 = __builtin_nontemporal_load((const i32x4*)(csr + iB));
    i32x4 rb1 = __builtin_nontemporal_load((const i32x4*)(csr + iB + 4));
    unsigned int uA0 = xs8[(size_t)ra0.x * 64 + l];
    unsigned int uA1 = xs8[(size_t)ra0.y * 64 + l];
    unsigned int uA2 = xs8[(size_t)ra0.z * 64 + l];
    unsigned int uA3 = xs8[(size_t)ra0.w * 64 + l];
    unsigned int uA4 = xs8[(size_t)ra1.x * 64 + l];
    unsigned int uA5 = xs8[(size_t)ra1.y * 64 + l];
    unsigned int uA6 = xs8[(size_t)ra1.z * 64 + l];
    unsigned int uA7 = xs8[(size_t)ra1.w * 64 + l];
    unsigned int uB0 = xs8[(size_t)rb0.x * 64 + l];
    unsigned int uB1 = xs8[(size_t)rb0.y * 64 + l];
    unsigned int uB2 = xs8[(size_t)rb0.z * 64 + l];
    unsigned int uB3 = xs8[(size_t)rb0.w * 64 + l];
    unsigned int uB4 = xs8[(size_t)rb1.x * 64 + l];
    unsigned int uB5 = xs8[(size_t)rb1.y * 64 + l];
    unsigned int uB6 = xs8[(size_t)rb1.z * 64 + l];
    unsigned int uB7 = xs8[(size_t)rb1.w * 64 + l];
    DECACC(uA0, aA0, aA1, aA2, aA3); DECACC(uA1, aA0, aA1, aA2, aA3);
    DECACC(uA2, aA0, aA1, aA2, aA3); DECACC(uA3, aA0, aA1, aA2, aA3);
    DECACC(uA4, aA0, aA1, aA2, aA3); DECACC(uA5, aA0, aA1, aA2, aA3);
    DECACC(uA6, aA0, aA1, aA2, aA3); DECACC(uA7, aA0, aA1, aA2, aA3);
    DECACC(uB0, aB0, aB1, aB2, aB3); DECACC(uB1, aB0, aB1, aB2, aB3);
    DECACC(uB2, aB0, aB1, aB2, aB3); DECACC(uB3, aB0, aB1, aB2, aB3);
    DECACC(uB4, aB0, aB1, aB2, aB3); DECACC(uB5, aB0, aB1, aB2, aB3);
    DECACC(uB6, aB0, aB1, aB2, aB3); DECACC(uB7, aB0, aB1, aB2, aB3);
    iA += 8; iB += 8;
  }
  // 8-wide single-node drains (one node much denser than the other)
  while (iA + 8 <= eA) {
    i32x4 r0 = __builtin_nontemporal_load((const i32x4*)(csr + iA));
    i32x4 r1 = __builtin_nontemporal_load((const i32x4*)(csr + iA + 4));
    unsigned int u0 = xs8[(size_t)r0.x * 64 + l];
    unsigned int u1 = xs8[(size_t)r0.y * 64 + l];
    unsigned int u2 = xs8[(size_t)r0.z * 64 + l];
    unsigned int u3 = xs8[(size_t)r0.w * 64 + l];
    unsigned int u4 = xs8[(size_t)r1.x * 64 + l];
    unsigned int u5 = xs8[(size_t)r1.y * 64 + l];
    unsigned int u6 = xs8[(size_t)r1.z * 64 + l];
    unsigned int u7 = xs8[(size_t)r1.w * 64 + l];
    DECACC(u0, aA0, aA1, aA2, aA3); DECACC(u1, aA0, aA1, aA2, aA3);
    DECACC(u2, aA0, aA1, aA2, aA3); DECACC(u3, aA0, aA1, aA2, aA3);
    DECACC(u4, aA0, aA1, aA2, aA3); DECACC(u5, aA0, aA1, aA2, aA3);
    DECACC(u6, aA0, aA1, aA2, aA3); DECACC(u7, aA0, aA1, aA2, aA3);
    iA += 8;
  }
  while (iB + 8 <= eB) {
    i32x4 r0 = __builtin_nontemporal_load((const i32x4*)(csr + iB));
    i32x4 r1 = __builtin_nontemporal_load((const i32x4*)(csr + iB + 4));
    unsigned int u0 = xs8[(size_t)r0.x * 64 + l];
    unsigned int u1 = xs8[(size_t)r0.y * 64 + l];
    unsigned int u2 = xs8[(size_t)r0.z * 64 + l];
    unsigned int u3 = xs8[(size_t)r0.w * 64 + l];
    unsigned int u4 = xs8[(size_t)r1.x * 64 + l];
    unsigned int u5 = xs8[(size_t)r1.y * 64 + l];
    unsigned int u6 = xs8[(size_t)r1.z * 64 + l];
    unsigned int u7 = xs8[(size_t)r1.w * 64 + l];
    DECACC(u0, aB0, aB1, aB2, aB3); DECACC(u1, aB0, aB1, aB2, aB3);
    DECACC(u2, aB0, aB1, aB2, aB3); DECACC(u3, aB0, aB1, aB2, aB3);
    DECACC(u4, aB0, aB1, aB2, aB3); DECACC(u5, aB0, aB1, aB2, aB3);
    DECACC(u6, aB0, aB1, aB2, aB3); DECACC(u7, aB0, aB1, aB2, aB3);
    iB += 8;
  }
  // 4-wide drains
  while (iA + 4 <= eA) {
    i32x4 r0 = __builtin_nontemporal_load((const i32x4*)(csr + iA));
    unsigned int u0 = xs8[(size_t)r0.x * 64 + l];
    unsigned int u1 = xs8[(size_t)r0.y * 64 + l];
    unsigned int u2 = xs8[(size_t)r0.z * 64 + l];
    unsigned int u3 = xs8[(size_t)r0.w * 64 + l];
    DECACC(u0, aA0, aA1, aA2, aA3); DECACC(u1, aA0, aA1, aA2, aA3);
    DECACC(u2, aA0, aA1, aA2, aA3); DECACC(u3, aA0, aA1, aA2, aA3);
    iA += 4;
  }
  while (iB + 4 <= eB) {
    i32x4 r0 = __builtin_nontemporal_load((const i32x4*)(csr + iB));
    unsigned int u0 = xs8[(size_t)r0.x * 64 + l];
    unsigned int u1 = xs8[(size_t)r0.y * 64 + l];
    unsigned int u2 = xs8[(size_t)r0.z * 64 + l];
    unsigned int u3 = xs8[(size_t)r0.w * 64 + l];
    DECACC(u0, aB0, aB1, aB2, aB3); DECACC(u1, aB0, aB1, aB2, aB3);
    DECACC(u2, aB0, aB1, aB2, aB3); DECACC(u3, aB0, aB1, aB2, aB3);
    iB += 4;
  }
  // scalar tails
  for (; iA < eA; ++iA) {
    unsigned int u = xs8[(size_t)csr[iA] * 64 + l];
    DECACC(u, aA0, aA1, aA2, aA3);
  }
  for (; iB < eB; ++iB) {
    unsigned int u = xs8[(size_t)csr[iB] * 64 + l];
    DECACC(u, aB0, aB1, aB2, aB3);
  }

  {
    ushort4 o;
    o.x = f2bf(aA0); o.y = f2bf(aA1); o.z = f2bf(aA2); o.w = f2bf(aA3);
    *(ushort4*)&xa[(2 * w) * 4 + (l >> 4)][(l & 15) * 4] = o;  // row = node_local*4+batch
    o.x = f2bf(aB0); o.y = f2bf(aB1); o.z = f2bf(aB2); o.w = f2bf(aB3);
    *(ushort4*)&xa[(2 * w + 1) * 4 + (l >> 4)][(l & 15) * 4] = o;
  }

  int m = l & 15, q = l >> 4;
  const unsigned short* wlin = wb16;
  const unsigned short* bigw = wb16 + 4096;

  // prefetch weights/bias/dis into registers BEFORE the barrier -> latency hides
  bf16x8 wa0  = *(const bf16x8*)(wlin + (16 * w + m) * 64 + q * 8);
  bf16x8 wa1  = *(const bf16x8*)(wlin + (16 * w + m) * 64 + q * 8 + 32);
  bf16x8 wb00 = *(const bf16x8*)(bigw + (32 * w + m) * 64 + q * 8);        // mt=0,kk=0
  bf16x8 wb10 = *(const bf16x8*)(bigw + (32 * w + 16 + m) * 64 + q * 8);   // mt=1,kk=0
  bf16x8 wb01 = *(const bf16x8*)(bigw + (32 * w + m) * 64 + q * 8 + 32);   // mt=0,kk=1
  bf16x8 wb11 = *(const bf16x8*)(bigw + (32 * w + 16 + m) * 64 + q * 8 + 32);
  float4 b4 = *(const float4*)(bias + 16 * w + 4 * q);
  float ds0 = dis[n0 + (m >> 2)];       // nt=0: row=m
  float ds1 = dis[n0 + 4 + (m >> 2)];   // nt=1: row=16+m

  __syncthreads();

  // stage1 (swapped): D[feat=16w+4q+reg][row=16nt+m]; fst = sigmoid(h*dis+bias)
  {
    f32x4 acc10 = {0, 0, 0, 0}, acc11 = {0, 0, 0, 0};
    bf16x8 x00 = *(const bf16x8*)&xa[m][q * 8];
    bf16x8 x10 = *(const bf16x8*)&xa[16 + m][q * 8];
    acc10 = __builtin_amdgcn_mfma_f32_16x16x32_bf16(wa0, x00, acc10, 0, 0, 0);
    acc11 = __builtin_amdgcn_mfma_f32_16x16x32_bf16(wa0, x10, acc11, 0, 0, 0);
    bf16x8 x01 = *(const bf16x8*)&xa[m][q * 8 + 32];
    bf16x8 x11 = *(const bf16x8*)&xa[16 + m][q * 8 + 32];
    acc10 = __builtin_amdgcn_mfma_f32_16x16x32_bf16(wa1, x01, acc10, 0, 0, 0);
    acc11 = __builtin_amdgcn_mfma_f32_16x16x32_bf16(wa1, x11, acc11, 0, 0, 0);
    {
      float v0 = acc10[0] * ds0 + b4.x;
      float v1 = acc10[1] * ds0 + b4.y;
      float v2 = acc10[2] * ds0 + b4.z;
      float v3 = acc10[3] * ds0 + b4.w;
      ushort4 o;
      o.x = f2bf(1.f / (1.f + __expf(-v0)));
      o.y = f2bf(1.f / (1.f + __expf(-v1)));
      o.z = f2bf(1.f / (1.f + __expf(-v2)));
      o.w = f2bf(1.f / (1.f + __expf(-v3)));
      *(ushort4*)&fst[m][16 * w + 4 * q] = o;
    }
    {
      float v0 = acc11[0] * ds1 + b4.x;
      float v1 = acc11[1] * ds1 + b4.y;
      float v2 = acc11[2] * ds1 + b4.z;
      float v3 = acc11[3] * ds1 + b4.w;
      ushort4 o;
      o.x = f2bf(1.f / (1.f + __expf(-v0)));
      o.y = f2bf(1.f / (1.f + __expf(-v1)));
      o.z = f2bf(1.f / (1.f + __expf(-v2)));
      o.w = f2bf(1.f / (1.f + __expf(-v3)));
      *(ushort4*)&fst[16 + m][16 * w + 4 * q] = o;
    }
  }
  __syncthreads();

  // stage2 (natural): D[row=16nt+4q+reg][oc=32w+16mt+m] -> full-line stores
  {
    f32x4 a00 = {0, 0, 0, 0}, a01 = {0, 0, 0, 0};  // a<mt><nt>
    f32x4 a10 = {0, 0, 0, 0}, a11 = {0, 0, 0, 0};
    bf16x8 f00 = *(const bf16x8*)&fst[m][q * 8];          // nt=0, kk=0
    bf16x8 f10 = *(const bf16x8*)&fst[16 + m][q * 8];     // nt=1, kk=0
    a00 = __builtin_amdgcn_mfma_f32_16x16x32_bf16(f00, wb00, a00, 0, 0, 0);
    a10 = __builtin_amdgcn_mfma_f32_16x16x32_bf16(f00, wb10, a10, 0, 0, 0);
    a01 = __builtin_amdgcn_mfma_f32_16x16x32_bf16(f10, wb00, a01, 0, 0, 0);
    a11 = __builtin_amdgcn_mfma_f32_16x16x32_bf16(f10, wb10, a11, 0, 0, 0);
    bf16x8 f01 = *(const bf16x8*)&fst[m][q * 8 + 32];     // nt=0, kk=1
    bf16x8 f11 = *(const bf16x8*)&fst[16 + m][q * 8 + 32];// nt=1, kk=1
    a00 = __builtin_amdgcn_mfma_f32_16x16x32_bf16(f01, wb01, a00, 0, 0, 0);
    a10 = __builtin_amdgcn_mfma_f32_16x16x32_bf16(f01, wb11, a10, 0, 0, 0);
    a01 = __builtin_amdgcn_mfma_f32_16x16x32_bf16(f11, wb01, a01, 0, 0, 0);
    a11 = __builtin_amdgcn_mfma_f32_16x16x32_bf16(f11, wb11, a11, 0, 0, 0);

#pragma unroll
    for (int mt = 0; mt < 2; ++mt)
#pragma unroll
      for (int nt = 0; nt < 2; ++nt) {
        f32x4 acc = mt == 0 ? (nt == 0 ? a00 : a01) : (nt == 0 ? a10 : a11);
#pragma unroll
        for (int r = 0; r < 4; ++r) {
          int row = 16 * nt + 4 * q + r;  // lanes m=0..15 share this row
          int n = n0 + (row >> 2), b = row & 3;
          float v = acc[r];
          __builtin_nontemporal_store(
              v > 0.f ? v : 0.f,
              out + ((size_t)b * NODES + n) * 128 + 32 * w + 16 * mt + m);
        }
      }
  }
}

extern "C" void kernel_launch(void* const* d_in, const int* in_sizes, int n_in,
                              void* d_out, int out_size, void* d_ws, size_t ws_size,
                              hipStream_t stream) {
  const float* x     = (const float*)d_in[0];
  const int*   ei    = (const int*)d_in[1];
  const float* lin_w = (const float*)d_in[2];
  const float* bias  = (const float*)d_in[3];
  const float* up1   = (const float*)d_in[4];
  const float* up2   = (const float*)d_in[5];
  const float* lo1   = (const float*)d_in[6];
  const float* lo2   = (const float*)d_in[7];
  const float* lastw = (const float*)d_in[8];
  float* out = (float*)d_out;

  char* ws = (char*)d_ws;
  unsigned short* wb16 = (unsigned short*)(ws);            // 24576 B
  float* dis        = (float*)(ws + (64 << 10));           // 80 KB
  int*   cnt        = (int*)(ws + (192 << 10));            // 80 KB
  int*   csr        = (int*)(ws + (1 << 20));              // NODES*CAP*4 = 5.12 MB
  unsigned int* xs8 = (unsigned int*)(ws + (8 << 20));     // NODES*256 B = 5.12 MB

  (void)hipMemsetAsync(cnt, 0, NODES * sizeof(int), stream);
  k_build<<<NEB + LINB + BIGB, 256, 0, stream>>>(ei, cnt, csr, lin_w, up1, up2,
                                                 lo1, lo2, lastw, wb16);
  k_xconv<<<NODES / 4, 256, 0, stream>>>(cnt, dis, x, xs8);
  k_gpost<<<NODES / 8, 256, 0, stream>>>(cnt, csr, xs8, dis, bias, wb16, out);
}